// Round 16
// baseline (706.275 us; speedup 1.0000x reference)
//
#include <hip/hip_runtime.h>
#include <cstdint>
#include <cstddef>

// Problem constants (graph is fixed by the harness reference)
#define E1C 114688   // phase-1 edges = 2048*56
#define MMC 16384    // message nodes (and phase-2 edges)
#define NVC 2048     // variables
#define NSTEPS 10

typedef __bf16 bf16x8 __attribute__((ext_vector_type(8)));
typedef float  f32x4  __attribute__((ext_vector_type(4)));

__device__ __forceinline__ float sigm(float x) { return 1.0f / (1.0f + expf(-x)); }
__device__ __forceinline__ bf16x8 ld8(const __bf16* p) {
  return *reinterpret_cast<const bf16x8*>(p);
}

// ---------- weight pack: fp32 [N][Kin] row-major -> bf16 MFMA-B-fragment order ----------
#define NJOBS 13
struct PrepJobs {
  const float* src[NJOBS];
  __bf16* dst0;
  int kin[NJOBS];
  int nin[NJOBS];
  int ntile[NJOBS];
  int base[NJOBS];
  int total;
};

__global__ __launch_bounds__(256) void k_prep_all(PrepJobs J) {
  int gid = blockIdx.x * 256 + threadIdx.x;
  if (gid >= J.total) return;
  int jb = 0;
  #pragma unroll
  for (int x = 1; x < NJOBS; ++x) if (gid >= J.base[x]) jb = x;
  int d = gid - J.base[jb];
  int group = d >> 9, rr = d & 511, ln = rr >> 3, j = rr & 7;
  int q = ln >> 4, m16 = ln & 15;
  int NT = J.ntile[jb];
  int kc = group / NT, nt = group - kc * NT;
  int n = nt * 16 + m16, k = kc * 32 + q * 8 + j;
  int kin = J.kin[jb];
  float v = (k < kin && n < J.nin[jb]) ? J.src[jb][(size_t)n * kin + k] : 0.f;
  J.dst0[gid] = (__bf16)v;
}

// ---------- phase-1 edge MLP + IN-BLOCK unnormalized aggregation ----------
// (256,3): the MTILES=7 body holds ~96 live VGPRs of B-frags+accs — a (256,4)
// 128-VGPR cap forces spills in the hot MFMA loop (R15 regression, -44us). Keep 3.
template<int FDIM, int EPB, int MODE>
__global__ __launch_bounds__(256, 3) void k_mlp(
    const float* __restrict__ hA, const float* __restrict__ hB,
    const int* __restrict__ rowIdx, const int* __restrict__ colIdx,
    const float* __restrict__ feat,
    const __bf16* __restrict__ W1f, const float* __restrict__ b1,
    const __bf16* __restrict__ W2f, const float* __restrict__ b2,
    const __bf16* __restrict__ W3f, const float* __restrict__ b3,
    const float* __restrict__ attnW, const float* __restrict__ attnB,
    float* __restrict__ xout, float* __restrict__ Zpart)
{
  constexpr int RPW = EPB / 4;
  constexpr int MTILES = EPB / 16;
  constexpr int LPE = (EPB == 112) ? 2 : 4;
  constexpr int ACT = RPW * LPE;
  constexpr int ND = 128 / LPE;
  __shared__ __align__(16) __bf16 Xs[EPB][168];
  __shared__ float wexp[EPB];
  __shared__ float zp[4];
  __shared__ int mloc[16];
  const int t = threadIdx.x, lane = t & 63, w = t >> 6;
  const int r0 = w * RPW;
  const int e0 = blockIdx.x * EPB;

  {
    const int half = lane >> 5, l2 = lane & 31;
    const float* hbase = half ? hB : hA;
    const int* ibase = half ? colIdx : rowIdx;
    #pragma unroll
    for (int i = 0; i < RPW; ++i) {
      int e = r0 + i;
      int idx = ibase[e0 + e];
      float2 v = *reinterpret_cast<const float2*>(hbase + (size_t)idx * 64 + l2 * 2);
      union { __bf16 b[2]; unsigned u; } cv;
      cv.b[0] = (__bf16)v.x; cv.b[1] = (__bf16)v.y;
      *reinterpret_cast<unsigned*>(&Xs[e][half * 64 + l2 * 2]) = cv.u;
    }
    #pragma unroll
    for (int it = 0; it < RPW / 2; ++it) {
      int e = r0 + it * 2 + (lane >> 5);
      int f = lane & 31;
      float fv = (f < FDIM) ? feat[(size_t)(e0 + e) * FDIM + f] : 0.f;
      Xs[e][128 + f] = (__bf16)fv;
    }
  }

  if (MODE == 0 && t < 16) {
    int v = blockIdx.x * 2 + (t >> 3), b = t & 7;
    mloc[t] = colIdx[v * 56 + (b == 0 ? 7 : b - 1)];
  }

  {
    int eL = r0 + lane / LPE, part = lane % LPE;
    bool act = (lane < ACT);
    float s = 0.f;
    if (act) {
      #pragma unroll
      for (int jj = 0; jj < ND / 8; ++jj) {
        bf16x8 xv = ld8(&Xs[eL][part * ND + jj * 8]);
        #pragma unroll
        for (int j = 0; j < 8; ++j) s += attnW[part * ND + jj * 8 + j] * (float)xv[j];
      }
    }
    s += __shfl_xor(s, 1);
    if (LPE == 4) s += __shfl_xor(s, 2);
    float ex = 0.f;
    if (act && part == 0) {
      float le = s + attnB[0];
      le = le > 0.f ? le : 0.01f * le;
      ex = expf(le);
      wexp[eL] = ex;
    }
    #pragma unroll
    for (int off = 1; off < 64; off <<= 1) ex += __shfl_xor(ex, off);
    if (lane == 0) zp[w] = ex;
  }
  __syncthreads();
  if (t == 0) Zpart[blockIdx.x] = zp[0] + zp[1] + zp[2] + zp[3];

  const int m16 = lane & 15, q = lane >> 4;

  // layer 1: K=160
  {
    bf16x8 B0[5], B1[5];
    #pragma unroll
    for (int kc = 0; kc < 5; ++kc) {
      B0[kc] = ld8(W1f + (size_t)(kc * 8 + w * 2 + 0) * 512 + lane * 8);
      B1[kc] = ld8(W1f + (size_t)(kc * 8 + w * 2 + 1) * 512 + lane * 8);
    }
    f32x4 a0[MTILES], a1[MTILES];
    float bv0 = b1[(w * 2) * 16 + m16], bv1 = b1[(w * 2 + 1) * 16 + m16];
    #pragma unroll
    for (int mt = 0; mt < MTILES; ++mt) {
      a0[mt] = (f32x4){bv0, bv0, bv0, bv0};
      a1[mt] = (f32x4){bv1, bv1, bv1, bv1};
      #pragma unroll
      for (int kc = 0; kc < 5; ++kc) {
        bf16x8 av = ld8(&Xs[mt * 16 + m16][kc * 32 + q * 8]);
        a0[mt] = __builtin_amdgcn_mfma_f32_16x16x32_bf16(av, B0[kc], a0[mt], 0, 0, 0);
        a1[mt] = __builtin_amdgcn_mfma_f32_16x16x32_bf16(av, B1[kc], a1[mt], 0, 0, 0);
      }
    }
    __syncthreads();
    #pragma unroll
    for (int mt = 0; mt < MTILES; ++mt)
      #pragma unroll
      for (int r2 = 0; r2 < 4; ++r2) {
        float v0 = a0[mt][r2]; v0 = v0 > 0.f ? v0 : 0.f;
        float v1 = a1[mt][r2]; v1 = v1 > 0.f ? v1 : 0.f;
        Xs[mt * 16 + q * 4 + r2][(w * 2) * 16 + m16]     = (__bf16)v0;
        Xs[mt * 16 + q * 4 + r2][(w * 2 + 1) * 16 + m16] = (__bf16)v1;
      }
    __syncthreads();
  }

  // layer 2: K=128
  {
    bf16x8 B0[4], B1[4];
    #pragma unroll
    for (int kc = 0; kc < 4; ++kc) {
      B0[kc] = ld8(W2f + (size_t)(kc * 8 + w * 2 + 0) * 512 + lane * 8);
      B1[kc] = ld8(W2f + (size_t)(kc * 8 + w * 2 + 1) * 512 + lane * 8);
    }
    f32x4 a0[MTILES], a1[MTILES];
    float bv0 = b2[(w * 2) * 16 + m16], bv1 = b2[(w * 2 + 1) * 16 + m16];
    #pragma unroll
    for (int mt = 0; mt < MTILES; ++mt) {
      a0[mt] = (f32x4){bv0, bv0, bv0, bv0};
      a1[mt] = (f32x4){bv1, bv1, bv1, bv1};
      #pragma unroll
      for (int kc = 0; kc < 4; ++kc) {
        bf16x8 av = ld8(&Xs[mt * 16 + m16][kc * 32 + q * 8]);
        a0[mt] = __builtin_amdgcn_mfma_f32_16x16x32_bf16(av, B0[kc], a0[mt], 0, 0, 0);
        a1[mt] = __builtin_amdgcn_mfma_f32_16x16x32_bf16(av, B1[kc], a1[mt], 0, 0, 0);
      }
    }
    __syncthreads();
    #pragma unroll
    for (int mt = 0; mt < MTILES; ++mt)
      #pragma unroll
      for (int r2 = 0; r2 < 4; ++r2) {
        float v0 = a0[mt][r2]; v0 = v0 > 0.f ? v0 : 0.f;
        float v1 = a1[mt][r2]; v1 = v1 > 0.f ? v1 : 0.f;
        Xs[mt * 16 + q * 4 + r2][(w * 2) * 16 + m16]     = (__bf16)v0;
        Xs[mt * 16 + q * 4 + r2][(w * 2 + 1) * 16 + m16] = (__bf16)v1;
      }
    __syncthreads();
  }

  // layer 3: K=128, N=64
  f32x4 a3[MTILES];
  {
    bf16x8 B3[4];
    #pragma unroll
    for (int kc = 0; kc < 4; ++kc)
      B3[kc] = ld8(W3f + (size_t)(kc * 4 + w) * 512 + lane * 8);
    float bv = b3[w * 16 + m16];
    #pragma unroll
    for (int mt = 0; mt < MTILES; ++mt) {
      a3[mt] = (f32x4){bv, bv, bv, bv};
      #pragma unroll
      for (int kc = 0; kc < 4; ++kc) {
        bf16x8 av = ld8(&Xs[mt * 16 + m16][kc * 32 + q * 8]);
        a3[mt] = __builtin_amdgcn_mfma_f32_16x16x32_bf16(av, B3[kc], a3[mt], 0, 0, 0);
      }
    }
  }
  __syncthreads();

  float* Ms = reinterpret_cast<float*>(&Xs[0][0]);
  #pragma unroll
  for (int mt = 0; mt < MTILES; ++mt)
    #pragma unroll
    for (int r2 = 0; r2 < 4; ++r2) {
      int e = mt * 16 + q * 4 + r2;
      Ms[e * 68 + w * 16 + m16] = wexp[e] * a3[mt][r2];
    }
  __syncthreads();

  if (MODE == 0) {
    int node = t >> 4, cg = t & 15;
    int vloc = node >> 3, b = node & 7;
    float4 s4 = make_float4(0.f, 0.f, 0.f, 0.f);
    #pragma unroll
    for (int a1 = 0; a1 < 7; ++a1) {
      int a = a1 + (a1 >= b ? 1 : 0);
      int e = vloc * 56 + a * 7 + b - (b > a ? 1 : 0);
      float4 mv = *reinterpret_cast<const float4*>(Ms + e * 68 + cg * 4);
      s4.x += mv.x; s4.y += mv.y; s4.z += mv.z; s4.w += mv.w;
    }
    *reinterpret_cast<float4*>(xout + (size_t)mloc[node] * 64 + cg * 4) = s4;
  } else {
    constexpr int WIT = (EPB * 16) / 256;
    #pragma unroll
    for (int it = 0; it < WIT; ++it) {
      int idx = t + it * 256;
      int ml = idx >> 4, cg = idx & 15;
      float4 v = *reinterpret_cast<const float4*>(Ms + (ml ^ 1) * 68 + cg * 4);
      *reinterpret_cast<float4*>(xout + (size_t)(e0 + ml) * 64 + cg * 4) = v;
    }
  }
}

// ---------- gru1 + phase-2 attention tail (128 threads / 32 nodes / 512 blocks) ----------
__global__ __launch_bounds__(128) void k_gru_att(
    const float* __restrict__ xt, const float* __restrict__ Zp, int zn,
    float* __restrict__ hbuf, const float* __restrict__ hOther,
    const float* __restrict__ attnW, const float* __restrict__ attnB,
    const __bf16* __restrict__ WiF, const __bf16* __restrict__ WhF,
    const float* __restrict__ bi, const float* __restrict__ bh,
    float* __restrict__ eatt2, float* __restrict__ Zp2)
{
  __shared__ __align__(16) __bf16 xsf[2048];
  __shared__ __align__(16) __bf16 hsf[2048];
  __shared__ float hs32[32][68];
  __shared__ float zred[2];
  __shared__ float zp2s[2];
  const int t = threadIdx.x, lane = t & 63, w = t >> 6;
  const int n0 = blockIdx.x * 32;

  {
    float zs = 0.f;
    for (int i = t; i < zn; i += 128) zs += Zp[i];
    #pragma unroll
    for (int off = 32; off; off >>= 1) zs += __shfl_down(zs, off);
    if (lane == 0) zred[w] = zs;
  }
  __syncthreads();
  const float invZ = 1.0f / (zred[0] + zred[1]);

  {
    const int i = t >> 2, cb = t & 3;          // node i in [0,32)
    const float4* xp = (const float4*)(xt + (size_t)(n0 + i) * 64 + cb * 16);
    float4 x4[4] = {xp[0], xp[1], xp[2], xp[3]};
    #pragma unroll
    for (int k = 0; k < 4; ++k) {
      x4[k].x *= invZ; x4[k].y *= invZ; x4[k].z *= invZ; x4[k].w *= invZ;
    }
    const float* xf = (const float*)x4;
    #pragma unroll
    for (int half = 0; half < 2; ++half) {
      __bf16 v8[8];
      #pragma unroll
      for (int j = 0; j < 8; ++j) v8[j] = (__bf16)xf[half * 8 + j];
      int addr = (i >> 4) * 1024 + (cb >> 1) * 512 + ((cb & 1) * 2 + half) * 128 + (i & 15) * 8;
      *(uint4*)(xsf + addr) = *(const uint4*)v8;
    }
    const float4* hp = (const float4*)(hbuf + (size_t)(n0 + i) * 64 + cb * 16);
    float4 h4[4] = {hp[0], hp[1], hp[2], hp[3]};
    *(float4*)(&hs32[i][cb * 16 + 0])  = h4[0];
    *(float4*)(&hs32[i][cb * 16 + 4])  = h4[1];
    *(float4*)(&hs32[i][cb * 16 + 8])  = h4[2];
    *(float4*)(&hs32[i][cb * 16 + 12]) = h4[3];
    const float* hf = (const float*)h4;
    #pragma unroll
    for (int half = 0; half < 2; ++half) {
      __bf16 v8[8];
      #pragma unroll
      for (int j = 0; j < 8; ++j) v8[j] = (__bf16)hf[half * 8 + j];
      int addr = (i >> 4) * 1024 + (cb >> 1) * 512 + ((cb & 1) * 2 + half) * 128 + (i & 15) * 8;
      *(uint4*)(hsf + addr) = *(const uint4*)v8;
    }
  }
  __syncthreads();

  const int m16 = lane & 15, q = lane >> 4;
  f32x4 gi[12], gh[12];
  #pragma unroll
  for (int nt = 0; nt < 12; ++nt) { gi[nt] = (f32x4){0,0,0,0}; gh[nt] = (f32x4){0,0,0,0}; }
  #pragma unroll
  for (int kc = 0; kc < 2; ++kc) {
    bf16x8 ax = ld8(xsf + w * 1024 + kc * 512 + lane * 8);
    bf16x8 ah = ld8(hsf + w * 1024 + kc * 512 + lane * 8);
    #pragma unroll
    for (int nt = 0; nt < 12; ++nt) {
      bf16x8 bx = ld8(WiF + (size_t)(kc * 12 + nt) * 512 + lane * 8);
      gi[nt] = __builtin_amdgcn_mfma_f32_16x16x32_bf16(ax, bx, gi[nt], 0, 0, 0);
      bf16x8 bh8 = ld8(WhF + (size_t)(kc * 12 + nt) * 512 + lane * 8);
      gh[nt] = __builtin_amdgcn_mfma_f32_16x16x32_bf16(ah, bh8, gh[nt], 0, 0, 0);
    }
  }

  #pragma unroll
  for (int nt = 0; nt < 4; ++nt) {
    int o = nt * 16 + m16;
    float bir = bi[o]       + bh[o];
    float biz = bi[64 + o]  + bh[64 + o];
    float bin = bi[128 + o], bhn = bh[128 + o];
    #pragma unroll
    for (int r = 0; r < 4; ++r) {
      int nl = w * 16 + q * 4 + r;
      float rg = sigm(gi[nt][r]     + gh[nt][r]     + bir);
      float zg = sigm(gi[nt + 4][r] + gh[nt + 4][r] + biz);
      float ng = tanhf(gi[nt + 8][r] + bin + rg * (gh[nt + 8][r] + bhn));
      float ho = hs32[nl][o];
      float res = (1.f - zg) * ng + zg * ho;
      hbuf[(size_t)(n0 + nl) * 64 + o] = res;
      hs32[nl][o] = res;                       // fp32 h_new for the attention tail
    }
  }
  __syncthreads();

  // ---- phase-2 attention: le = attnW[0:64].h_new[e] + attnW[64:128].h_f2v[e^1] + b ----
  {
    int e = w * 16 + (lane >> 2), part = lane & 3;
    float s = 0.f;
    if (part < 2) {
      #pragma unroll
      for (int j = 0; j < 32; ++j) s += attnW[part * 32 + j] * hs32[e][part * 32 + j];
    } else {
      const float* hj = hOther + (size_t)((n0 + e) ^ 1) * 64 + (part - 2) * 32;
      #pragma unroll
      for (int j = 0; j < 32; ++j) s += attnW[64 + (part - 2) * 32 + j] * hj[j];
    }
    s += __shfl_xor(s, 1); s += __shfl_xor(s, 2);
    float ex = 0.f;
    if (part == 0) {
      float le = s + attnB[0];
      le = le > 0.f ? le : 0.01f * le;
      ex = expf(le);
      eatt2[n0 + e] = ex;
    }
    #pragma unroll
    for (int off = 4; off < 64; off <<= 1) ex += __shfl_xor(ex, off);
    if (lane == 0) zp2s[w] = ex;
  }
  __syncthreads();
  if (t == 0) Zp2[blockIdx.x] = zp2s[0] + zp2s[1];
}

// ---------- FUSED mlp2 + gru2: weighted messages never leave LDS ----------
__global__ __launch_bounds__(256) void k_fuse(
    const float* __restrict__ hV, float* __restrict__ hF,
    const float* __restrict__ feat,
    const float* __restrict__ eatt2, const float* __restrict__ Zp2,
    const __bf16* __restrict__ W1f, const float* __restrict__ b1,
    const __bf16* __restrict__ W2f, const float* __restrict__ b2,
    const __bf16* __restrict__ W3f, const float* __restrict__ b3,
    const __bf16* __restrict__ WiF, const __bf16* __restrict__ WhF,
    const float* __restrict__ bi, const float* __restrict__ bh)
{
  __shared__ __align__(16) __bf16 Xs[64][168];   // 21504 B; aliased as fp32 Ms later
  __shared__ __align__(16) float hs32[64][68];   // 17408 B (old h_f2v, fp32)
  __shared__ __align__(16) __bf16 xsf[4096];     // 8192 B (GRU x frags)
  __shared__ __align__(16) __bf16 hsf[4096];     // 8192 B (GRU h frags)
  __shared__ float wexp[64];
  __shared__ float zred[4];
  const int t = threadIdx.x, lane = t & 63, w = t >> 6;
  const int n0 = blockIdx.x * 64;
  const int m16 = lane & 15, q = lane >> 4;

  // Z2 reduce (512 slots, 2 per thread)
  {
    float zs = Zp2[t] + Zp2[t + 256];
    #pragma unroll
    for (int off = 32; off; off >>= 1) zs += __shfl_down(zs, off);
    if (lane == 0) zred[w] = zs;
  }
  if (t < 64) wexp[t] = eatt2[n0 + t];

  // stage Xs (hi = h_v2f[m], hj = h_f2v[m^1], feat) + hs32 (old h_f2v[m], fp32)
  {
    const int half = lane >> 5, l2 = lane & 31;
    const int r0 = w * 16;
    #pragma unroll
    for (int i = 0; i < 16; ++i) {
      int e = r0 + i;
      const float* src = half ? (hF + (size_t)((n0 + e) ^ 1) * 64)
                              : (hV + (size_t)(n0 + e) * 64);
      float2 v = *reinterpret_cast<const float2*>(src + l2 * 2);
      union { __bf16 b[2]; unsigned u; } cv;
      cv.b[0] = (__bf16)v.x; cv.b[1] = (__bf16)v.y;
      *reinterpret_cast<unsigned*>(&Xs[e][half * 64 + l2 * 2]) = cv.u;
    }
    #pragma unroll
    for (int it = 0; it < 8; ++it) {
      int e = r0 + it * 2 + (lane >> 5);
      int f = lane & 31;
      float fv = (f < 4) ? feat[(size_t)(n0 + e) * 4 + f] : 0.f;
      Xs[e][128 + f] = (__bf16)fv;
    }
  }
  {
    const int i = t >> 2, cb = t & 3;
    const float4* hp = (const float4*)(hF + (size_t)(n0 + i) * 64 + cb * 16);
    *(float4*)(&hs32[i][cb * 16 + 0])  = hp[0];
    *(float4*)(&hs32[i][cb * 16 + 4])  = hp[1];
    *(float4*)(&hs32[i][cb * 16 + 8])  = hp[2];
    *(float4*)(&hs32[i][cb * 16 + 12]) = hp[3];
  }
  __syncthreads();
  const float invZ = 1.0f / (zred[0] + zred[1] + zred[2] + zred[3]);

  // ---- mlp2 layer 1: K=160 ----
  {
    bf16x8 B0[5], B1[5];
    #pragma unroll
    for (int kc = 0; kc < 5; ++kc) {
      B0[kc] = ld8(W1f + (size_t)(kc * 8 + w * 2 + 0) * 512 + lane * 8);
      B1[kc] = ld8(W1f + (size_t)(kc * 8 + w * 2 + 1) * 512 + lane * 8);
    }
    f32x4 a0[4], a1[4];
    float bv0 = b1[(w * 2) * 16 + m16], bv1 = b1[(w * 2 + 1) * 16 + m16];
    #pragma unroll
    for (int mt = 0; mt < 4; ++mt) {
      a0[mt] = (f32x4){bv0, bv0, bv0, bv0};
      a1[mt] = (f32x4){bv1, bv1, bv1, bv1};
      #pragma unroll
      for (int kc = 0; kc < 5; ++kc) {
        bf16x8 av = ld8(&Xs[mt * 16 + m16][kc * 32 + q * 8]);
        a0[mt] = __builtin_amdgcn_mfma_f32_16x16x32_bf16(av, B0[kc], a0[mt], 0, 0, 0);
        a1[mt] = __builtin_amdgcn_mfma_f32_16x16x32_bf16(av, B1[kc], a1[mt], 0, 0, 0);
      }
    }
    __syncthreads();
    #pragma unroll
    for (int mt = 0; mt < 4; ++mt)
      #pragma unroll
      for (int r2 = 0; r2 < 4; ++r2) {
        float v0 = a0[mt][r2]; v0 = v0 > 0.f ? v0 : 0.f;
        float v1 = a1[mt][r2]; v1 = v1 > 0.f ? v1 : 0.f;
        Xs[mt * 16 + q * 4 + r2][(w * 2) * 16 + m16]     = (__bf16)v0;
        Xs[mt * 16 + q * 4 + r2][(w * 2 + 1) * 16 + m16] = (__bf16)v1;
      }
    __syncthreads();
  }

  // ---- mlp2 layer 2: K=128 ----
  {
    bf16x8 B0[4], B1[4];
    #pragma unroll
    for (int kc = 0; kc < 4; ++kc) {
      B0[kc] = ld8(W2f + (size_t)(kc * 8 + w * 2 + 0) * 512 + lane * 8);
      B1[kc] = ld8(W2f + (size_t)(kc * 8 + w * 2 + 1) * 512 + lane * 8);
    }
    f32x4 a0[4], a1[4];
    float bv0 = b2[(w * 2) * 16 + m16], bv1 = b2[(w * 2 + 1) * 16 + m16];
    #pragma unroll
    for (int mt = 0; mt < 4; ++mt) {
      a0[mt] = (f32x4){bv0, bv0, bv0, bv0};
      a1[mt] = (f32x4){bv1, bv1, bv1, bv1};
      #pragma unroll
      for (int kc = 0; kc < 4; ++kc) {
        bf16x8 av = ld8(&Xs[mt * 16 + m16][kc * 32 + q * 8]);
        a0[mt] = __builtin_amdgcn_mfma_f32_16x16x32_bf16(av, B0[kc], a0[mt], 0, 0, 0);
        a1[mt] = __builtin_amdgcn_mfma_f32_16x16x32_bf16(av, B1[kc], a1[mt], 0, 0, 0);
      }
    }
    __syncthreads();
    #pragma unroll
    for (int mt = 0; mt < 4; ++mt)
      #pragma unroll
      for (int r2 = 0; r2 < 4; ++r2) {
        float v0 = a0[mt][r2]; v0 = v0 > 0.f ? v0 : 0.f;
        float v1 = a1[mt][r2]; v1 = v1 > 0.f ? v1 : 0.f;
        Xs[mt * 16 + q * 4 + r2][(w * 2) * 16 + m16]     = (__bf16)v0;
        Xs[mt * 16 + q * 4 + r2][(w * 2 + 1) * 16 + m16] = (__bf16)v1;
      }
    __syncthreads();
  }

  // ---- mlp2 layer 3: K=128, N=64 -> weighted msg into LDS Ms ----
  f32x4 a3[4];
  {
    bf16x8 B3[4];
    #pragma unroll
    for (int kc = 0; kc < 4; ++kc)
      B3[kc] = ld8(W3f + (size_t)(kc * 4 + w) * 512 + lane * 8);
    float bv = b3[w * 16 + m16];
    #pragma unroll
    for (int mt = 0; mt < 4; ++mt) {
      a3[mt] = (f32x4){bv, bv, bv, bv};
      #pragma unroll
      for (int kc = 0; kc < 4; ++kc) {
        bf16x8 av = ld8(&Xs[mt * 16 + m16][kc * 32 + q * 8]);
        a3[mt] = __builtin_amdgcn_mfma_f32_16x16x32_bf16(av, B3[kc], a3[mt], 0, 0, 0);
      }
    }
  }
  __syncthreads();
  float* Ms = reinterpret_cast<float*>(&Xs[0][0]);
  #pragma unroll
  for (int mt = 0; mt < 4; ++mt)
    #pragma unroll
    for (int r2 = 0; r2 < 4; ++r2) {
      int e = mt * 16 + q * 4 + r2;
      Ms[e * 68 + w * 16 + m16] = wexp[e] * a3[mt][r2];
    }
  __syncthreads();

  // ---- gru2: x[m] = Ms[m^1] * invZ; h from hs32 ----
  {
    const int i = t >> 2, cb = t & 3;
    float x16[16];
    #pragma unroll
    for (int k4 = 0; k4 < 4; ++k4) {
      float4 v = *reinterpret_cast<const float4*>(Ms + (i ^ 1) * 68 + cb * 16 + k4 * 4);
      x16[k4 * 4 + 0] = v.x * invZ; x16[k4 * 4 + 1] = v.y * invZ;
      x16[k4 * 4 + 2] = v.z * invZ; x16[k4 * 4 + 3] = v.w * invZ;
    }
    #pragma unroll
    for (int half = 0; half < 2; ++half) {
      __bf16 v8[8];
      #pragma unroll
      for (int j = 0; j < 8; ++j) v8[j] = (__bf16)x16[half * 8 + j];
      int addr = (i >> 4) * 1024 + (cb >> 1) * 512 + ((cb & 1) * 2 + half) * 128 + (i & 15) * 8;
      *(uint4*)(xsf + addr) = *(const uint4*)v8;
    }
    #pragma unroll
    for (int half = 0; half < 2; ++half) {
      __bf16 v8[8];
      #pragma unroll
      for (int j = 0; j < 8; ++j) v8[j] = (__bf16)hs32[i][cb * 16 + half * 8 + j];
      int addr = (i >> 4) * 1024 + (cb >> 1) * 512 + ((cb & 1) * 2 + half) * 128 + (i & 15) * 8;
      *(uint4*)(hsf + addr) = *(const uint4*)v8;
    }
  }
  __syncthreads();

  f32x4 gi[12], gh[12];
  #pragma unroll
  for (int nt = 0; nt < 12; ++nt) { gi[nt] = (f32x4){0,0,0,0}; gh[nt] = (f32x4){0,0,0,0}; }
  #pragma unroll
  for (int kc = 0; kc < 2; ++kc) {
    bf16x8 ax = ld8(xsf + w * 1024 + kc * 512 + lane * 8);
    bf16x8 ah = ld8(hsf + w * 1024 + kc * 512 + lane * 8);
    #pragma unroll
    for (int nt = 0; nt < 12; ++nt) {
      bf16x8 bx = ld8(WiF + (size_t)(kc * 12 + nt) * 512 + lane * 8);
      gi[nt] = __builtin_amdgcn_mfma_f32_16x16x32_bf16(ax, bx, gi[nt], 0, 0, 0);
      bf16x8 bh8 = ld8(WhF + (size_t)(kc * 12 + nt) * 512 + lane * 8);
      gh[nt] = __builtin_amdgcn_mfma_f32_16x16x32_bf16(ah, bh8, gh[nt], 0, 0, 0);
    }
  }

  #pragma unroll
  for (int nt = 0; nt < 4; ++nt) {
    int o = nt * 16 + m16;
    float bir = bi[o]       + bh[o];
    float biz = bi[64 + o]  + bh[64 + o];
    float bin = bi[128 + o], bhn = bh[128 + o];
    #pragma unroll
    for (int r = 0; r < 4; ++r) {
      int nl = w * 16 + q * 4 + r;
      float rg = sigm(gi[nt][r]     + gh[nt][r]     + bir);
      float zg = sigm(gi[nt + 4][r] + gh[nt + 4][r] + biz);
      float ng = tanhf(gi[nt + 8][r] + bin + rg * (gh[nt + 8][r] + bhn));
      float ho = hs32[nl][o];
      hF[(size_t)(n0 + nl) * 64 + o] = (1.f - zg) * ng + zg * ho;
    }
  }
}

// ---------- fused node-sum + readout MLP ----------
__global__ __launch_bounds__(256) void k_readout(
    const float* __restrict__ f2v_h, const int* __restrict__ f2v_col,
    const __bf16* __restrict__ W1f, const float* __restrict__ b1,
    const __bf16* __restrict__ W2f, const float* __restrict__ b2,
    const __bf16* __restrict__ W3f, const float* __restrict__ b3,
    float* __restrict__ out)
{
  __shared__ __align__(16) __bf16 Xs[64][136];
  const int t = threadIdx.x, lane = t & 63, w = t >> 6;
  const int r0 = w * 16;
  const int v0 = blockIdx.x * 64;

  #pragma unroll
  for (int i = 0; i < 16; ++i) {
    int v = v0 + r0 + i;
    float s = 0.f;
    #pragma unroll
    for (int b = 0; b < 8; ++b) {
      int m = f2v_col[v * 56 + (b == 0 ? 7 : (b - 1))];
      s += f2v_h[(size_t)m * 64 + lane];
    }
    Xs[r0 + i][lane] = (__bf16)s;
  }

  const int m16 = lane & 15, q = lane >> 4;

  {
    f32x4 acc[8];
    #pragma unroll
    for (int nt = 0; nt < 8; ++nt) {
      float bv = b1[nt * 16 + m16];
      acc[nt] = (f32x4){bv, bv, bv, bv};
    }
    #pragma unroll
    for (int kc = 0; kc < 2; ++kc) {
      bf16x8 av = ld8(&Xs[r0 + m16][kc * 32 + q * 8]);
      #pragma unroll
      for (int nt = 0; nt < 8; ++nt) {
        bf16x8 bv = ld8(W1f + (size_t)(kc * 8 + nt) * 512 + lane * 8);
        acc[nt] = __builtin_amdgcn_mfma_f32_16x16x32_bf16(av, bv, acc[nt], 0, 0, 0);
      }
    }
    #pragma unroll
    for (int nt = 0; nt < 8; ++nt)
      #pragma unroll
      for (int r2 = 0; r2 < 4; ++r2) {
        float v = acc[nt][r2]; v = v > 0.f ? v : 0.f;
        Xs[r0 + q * 4 + r2][nt * 16 + m16] = (__bf16)v;
      }
  }

  {
    f32x4 acc[8];
    #pragma unroll
    for (int nt = 0; nt < 8; ++nt) {
      float bv = b2[nt * 16 + m16];
      acc[nt] = (f32x4){bv, bv, bv, bv};
    }
    #pragma unroll
    for (int kc = 0; kc < 4; ++kc) {
      bf16x8 av = ld8(&Xs[r0 + m16][kc * 32 + q * 8]);
      #pragma unroll
      for (int nt = 0; nt < 8; ++nt) {
        bf16x8 bv = ld8(W2f + (size_t)(kc * 8 + nt) * 512 + lane * 8);
        acc[nt] = __builtin_amdgcn_mfma_f32_16x16x32_bf16(av, bv, acc[nt], 0, 0, 0);
      }
    }
    #pragma unroll
    for (int nt = 0; nt < 8; ++nt)
      #pragma unroll
      for (int r2 = 0; r2 < 4; ++r2) {
        float v = acc[nt][r2]; v = v > 0.f ? v : 0.f;
        Xs[r0 + q * 4 + r2][nt * 16 + m16] = (__bf16)v;
      }
  }

  {
    f32x4 acc = (f32x4){0, 0, 0, 0};
    if (m16 < 2) { float bv = b3[m16]; acc = (f32x4){bv, bv, bv, bv}; }
    #pragma unroll
    for (int kc = 0; kc < 4; ++kc) {
      bf16x8 av = ld8(&Xs[r0 + m16][kc * 32 + q * 8]);
      bf16x8 bv = ld8(W3f + (size_t)kc * 512 + lane * 8);
      acc = __builtin_amdgcn_mfma_f32_16x16x32_bf16(av, bv, acc, 0, 0, 0);
    }
    #pragma unroll
    for (int r = 0; r < 4; ++r) {
      float other = __shfl_xor(acc[r], 1);
      if (m16 == 0) {
        float l0 = acc[r], l1 = other;
        float mx = fmaxf(l0, l1);
        float p0 = expf(l0 - mx), p1 = expf(l1 - mx);
        float inv = 1.0f / (p0 + p1);
        int v = v0 + r0 + q * 4 + r;
        *reinterpret_cast<float2*>(out + (size_t)v * 2) = make_float2(p0 * inv, p1 * inv);
      }
    }
  }
}

extern "C" void kernel_launch(void* const* d_in, const int* in_sizes, int n_in,
                              void* d_out, int out_size, void* d_ws, size_t ws_size,
                              hipStream_t stream) {
  const float* attn_W = (const float*)d_in[0];
  const float* attn_b = (const float*)d_in[1];
  const float* v2f_W1 = (const float*)d_in[2];
  const float* v2f_b1 = (const float*)d_in[3];
  const float* v2f_W2 = (const float*)d_in[4];
  const float* v2f_b2 = (const float*)d_in[5];
  const float* v2f_W3 = (const float*)d_in[6];
  const float* v2f_b3 = (const float*)d_in[7];
  const float* f2v_W1 = (const float*)d_in[8];
  const float* f2v_b1 = (const float*)d_in[9];
  const float* f2v_W2 = (const float*)d_in[10];
  const float* f2v_b2 = (const float*)d_in[11];
  const float* f2v_W3 = (const float*)d_in[12];
  const float* f2v_b3 = (const float*)d_in[13];
  const float* ro_W1  = (const float*)d_in[14];
  const float* ro_b1  = (const float*)d_in[15];
  const float* ro_W2  = (const float*)d_in[16];
  const float* ro_b2  = (const float*)d_in[17];
  const float* ro_W3  = (const float*)d_in[18];
  const float* ro_b3  = (const float*)d_in[19];
  const float* gv_Wi  = (const float*)d_in[20];
  const float* gv_Wh  = (const float*)d_in[21];
  const float* gv_bi  = (const float*)d_in[22];
  const float* gv_bh  = (const float*)d_in[23];
  const float* gf_Wi  = (const float*)d_in[24];
  const float* gf_Wh  = (const float*)d_in[25];
  const float* gf_bi  = (const float*)d_in[26];
  const float* gf_bh  = (const float*)d_in[27];
  const float* feat5  = (const float*)d_in[28];
  const float* feat4  = (const float*)d_in[29];
  const int* f2v_row  = (const int*)d_in[30];
  const int* f2v_col  = (const int*)d_in[31];

  float* ws = (float*)d_ws;
  float* xt1    = ws;                                    // M*64
  float* h_v2f  = xt1 + (size_t)MMC * 64;                // M*64
  float* h_f2v  = h_v2f + (size_t)MMC * 64;              // M*64
  float* Zp1    = h_f2v + (size_t)MMC * 64;              // 1024
  float* Zp2    = Zp1 + 1024;                            // 512
  float* eatt2  = Zp2 + 512;                             // MMC
  __bf16* wbuf  = (__bf16*)(((uintptr_t)(eatt2 + MMC) + 15) & ~(uintptr_t)15);
  __bf16* w1v = wbuf;            // 20480
  __bf16* w2v = w1v + 20480;     // 16384
  __bf16* w3v = w2v + 16384;     //  8192
  __bf16* w1f = w3v + 8192;      // 20480
  __bf16* w2f = w1f + 20480;     // 16384
  __bf16* w3f = w2f + 16384;     //  8192
  __bf16* wiv = w3f + 8192;      // 12288
  __bf16* whv = wiv + 12288;     // 12288
  __bf16* wif = whv + 12288;     // 12288
  __bf16* whf = wif + 12288;     // 12288
  __bf16* wr1 = whf + 12288;     //  8192
  __bf16* wr2 = wr1 + 8192;      // 16384
  __bf16* wr3 = wr2 + 16384;     //  2048

  hipMemsetAsync(h_v2f, 0, (size_t)2 * MMC * 64 * sizeof(float), stream);

  {
    PrepJobs J;
    const float* srcs[NJOBS] = {v2f_W1, v2f_W2, v2f_W3, f2v_W1, f2v_W2, f2v_W3,
                                gv_Wi, gv_Wh, gf_Wi, gf_Wh, ro_W1, ro_W2, ro_W3};
    int kin[NJOBS]  = {133, 128, 128, 132, 128, 128, 64, 64, 64, 64, 64, 128, 128};
    int nin[NJOBS]  = {128, 128, 64, 128, 128, 64, 192, 192, 192, 192, 128, 128, 2};
    int nt[NJOBS]   = {8, 8, 4, 8, 8, 4, 12, 12, 12, 12, 8, 8, 1};
    int size[NJOBS] = {20480, 16384, 8192, 20480, 16384, 8192,
                       12288, 12288, 12288, 12288, 8192, 16384, 2048};
    int cum = 0;
    for (int i = 0; i < NJOBS; ++i) {
      J.src[i] = srcs[i]; J.kin[i] = kin[i]; J.nin[i] = nin[i]; J.ntile[i] = nt[i];
      J.base[i] = cum; cum += size[i];
    }
    J.dst0 = wbuf; J.total = cum;   // 165888
    k_prep_all<<<(cum + 255) / 256, 256, 0, stream>>>(J);
  }

  const int ZN1 = E1C / 112;        // 1024 block slots, phase 1

  for (int s = 0; s < NSTEPS; ++s) {
    // phase 1: edge MLP + in-block aggregation (112-edge = 2-variable tiles)
    k_mlp<5, 112, 0><<<E1C / 112, 256, 0, stream>>>(
        h_f2v, h_v2f, f2v_row, f2v_col, feat5,
        w1v, v2f_b1, w2v, v2f_b2, w3v, v2f_b3,
        attn_W, attn_b, xt1, Zp1);
    // gru1 (h_v2f update) + phase-2 attention (fp32 h) -> eatt2, Zp2 (512 blocks)
    k_gru_att<<<MMC / 32, 128, 0, stream>>>(
        xt1, Zp1, ZN1, h_v2f, h_f2v, attn_W, attn_b,
        wiv, whv, gv_bi, gv_bh, eatt2, Zp2);
    // fused mlp2 + gru2 (weighted msgs stay in LDS; h_f2v update)
    k_fuse<<<MMC / 64, 256, 0, stream>>>(
        h_v2f, h_f2v, feat4, eatt2, Zp2,
        w1f, f2v_b1, w2f, f2v_b2, w3f, f2v_b3,
        wif, whf, gf_bi, gf_bh);
  }
  k_readout<<<NVC / 64, 256, 0, stream>>>(h_f2v, f2v_col,
                                          wr1, ro_b1, wr2, ro_b2, wr3, ro_b3,
                                          (float*)d_out);
}

// Round 17
// 658.527 us; speedup vs baseline: 1.0725x; 1.0725x over previous
//
#include <hip/hip_runtime.h>
#include <cstdint>
#include <cstddef>

// Problem constants (graph is fixed by the harness reference)
#define E1C 114688   // phase-1 edges = 2048*56
#define MMC 16384    // message nodes (and phase-2 edges)
#define NVC 2048     // variables
#define NSTEPS 10

typedef __bf16 bf16x8 __attribute__((ext_vector_type(8)));
typedef float  f32x4  __attribute__((ext_vector_type(4)));

__device__ __forceinline__ float sigm(float x) { return 1.0f / (1.0f + expf(-x)); }
__device__ __forceinline__ bf16x8 ld8(const __bf16* p) {
  return *reinterpret_cast<const bf16x8*>(p);
}

// ---------- weight pack: fp32 [N][Kin] row-major -> bf16 MFMA-B-fragment order ----------
#define NJOBS 13
struct PrepJobs {
  const float* src[NJOBS];
  __bf16* dst0;
  int kin[NJOBS];
  int nin[NJOBS];
  int ntile[NJOBS];
  int base[NJOBS];
  int total;
};

__global__ __launch_bounds__(256) void k_prep_all(PrepJobs J) {
  int gid = blockIdx.x * 256 + threadIdx.x;
  if (gid >= J.total) return;
  int jb = 0;
  #pragma unroll
  for (int x = 1; x < NJOBS; ++x) if (gid >= J.base[x]) jb = x;
  int d = gid - J.base[jb];
  int group = d >> 9, rr = d & 511, ln = rr >> 3, j = rr & 7;
  int q = ln >> 4, m16 = ln & 15;
  int NT = J.ntile[jb];
  int kc = group / NT, nt = group - kc * NT;
  int n = nt * 16 + m16, k = kc * 32 + q * 8 + j;
  int kin = J.kin[jb];
  float v = (k < kin && n < J.nin[jb]) ? J.src[jb][(size_t)n * kin + k] : 0.f;
  J.dst0[gid] = (__bf16)v;
}

// ---------- phase-1 edge MLP + IN-BLOCK unnormalized aggregation (R14 verbatim) ----------
template<int FDIM, int EPB, int MODE>
__global__ __launch_bounds__(256, 3) void k_mlp(
    const float* __restrict__ hA, const float* __restrict__ hB,
    const int* __restrict__ rowIdx, const int* __restrict__ colIdx,
    const float* __restrict__ feat,
    const __bf16* __restrict__ W1f, const float* __restrict__ b1,
    const __bf16* __restrict__ W2f, const float* __restrict__ b2,
    const __bf16* __restrict__ W3f, const float* __restrict__ b3,
    const float* __restrict__ attnW, const float* __restrict__ attnB,
    float* __restrict__ xout, float* __restrict__ Zpart)
{
  constexpr int RPW = EPB / 4;
  constexpr int MTILES = EPB / 16;
  constexpr int LPE = (EPB == 112) ? 2 : 4;
  constexpr int ACT = RPW * LPE;
  constexpr int ND = 128 / LPE;
  __shared__ __align__(16) __bf16 Xs[EPB][168];
  __shared__ float wexp[EPB];
  __shared__ float zp[4];
  __shared__ int mloc[16];
  const int t = threadIdx.x, lane = t & 63, w = t >> 6;
  const int r0 = w * RPW;
  const int e0 = blockIdx.x * EPB;

  {
    const int half = lane >> 5, l2 = lane & 31;
    const float* hbase = half ? hB : hA;
    const int* ibase = half ? colIdx : rowIdx;
    #pragma unroll
    for (int i = 0; i < RPW; ++i) {
      int e = r0 + i;
      int idx = ibase[e0 + e];
      float2 v = *reinterpret_cast<const float2*>(hbase + (size_t)idx * 64 + l2 * 2);
      union { __bf16 b[2]; unsigned u; } cv;
      cv.b[0] = (__bf16)v.x; cv.b[1] = (__bf16)v.y;
      *reinterpret_cast<unsigned*>(&Xs[e][half * 64 + l2 * 2]) = cv.u;
    }
    #pragma unroll
    for (int it = 0; it < RPW / 2; ++it) {
      int e = r0 + it * 2 + (lane >> 5);
      int f = lane & 31;
      float fv = (f < FDIM) ? feat[(size_t)(e0 + e) * FDIM + f] : 0.f;
      Xs[e][128 + f] = (__bf16)fv;
    }
  }

  if (MODE == 0 && t < 16) {
    int v = blockIdx.x * 2 + (t >> 3), b = t & 7;
    mloc[t] = colIdx[v * 56 + (b == 0 ? 7 : b - 1)];
  }

  {
    int eL = r0 + lane / LPE, part = lane % LPE;
    bool act = (lane < ACT);
    float s = 0.f;
    if (act) {
      #pragma unroll
      for (int jj = 0; jj < ND / 8; ++jj) {
        bf16x8 xv = ld8(&Xs[eL][part * ND + jj * 8]);
        #pragma unroll
        for (int j = 0; j < 8; ++j) s += attnW[part * ND + jj * 8 + j] * (float)xv[j];
      }
    }
    s += __shfl_xor(s, 1);
    if (LPE == 4) s += __shfl_xor(s, 2);
    float ex = 0.f;
    if (act && part == 0) {
      float le = s + attnB[0];
      le = le > 0.f ? le : 0.01f * le;
      ex = expf(le);
      wexp[eL] = ex;
    }
    #pragma unroll
    for (int off = 1; off < 64; off <<= 1) ex += __shfl_xor(ex, off);
    if (lane == 0) zp[w] = ex;
  }
  __syncthreads();
  if (t == 0) Zpart[blockIdx.x] = zp[0] + zp[1] + zp[2] + zp[3];

  const int m16 = lane & 15, q = lane >> 4;

  // layer 1: K=160
  {
    bf16x8 B0[5], B1[5];
    #pragma unroll
    for (int kc = 0; kc < 5; ++kc) {
      B0[kc] = ld8(W1f + (size_t)(kc * 8 + w * 2 + 0) * 512 + lane * 8);
      B1[kc] = ld8(W1f + (size_t)(kc * 8 + w * 2 + 1) * 512 + lane * 8);
    }
    f32x4 a0[MTILES], a1[MTILES];
    float bv0 = b1[(w * 2) * 16 + m16], bv1 = b1[(w * 2 + 1) * 16 + m16];
    #pragma unroll
    for (int mt = 0; mt < MTILES; ++mt) {
      a0[mt] = (f32x4){bv0, bv0, bv0, bv0};
      a1[mt] = (f32x4){bv1, bv1, bv1, bv1};
      #pragma unroll
      for (int kc = 0; kc < 5; ++kc) {
        bf16x8 av = ld8(&Xs[mt * 16 + m16][kc * 32 + q * 8]);
        a0[mt] = __builtin_amdgcn_mfma_f32_16x16x32_bf16(av, B0[kc], a0[mt], 0, 0, 0);
        a1[mt] = __builtin_amdgcn_mfma_f32_16x16x32_bf16(av, B1[kc], a1[mt], 0, 0, 0);
      }
    }
    __syncthreads();
    #pragma unroll
    for (int mt = 0; mt < MTILES; ++mt)
      #pragma unroll
      for (int r2 = 0; r2 < 4; ++r2) {
        float v0 = a0[mt][r2]; v0 = v0 > 0.f ? v0 : 0.f;
        float v1 = a1[mt][r2]; v1 = v1 > 0.f ? v1 : 0.f;
        Xs[mt * 16 + q * 4 + r2][(w * 2) * 16 + m16]     = (__bf16)v0;
        Xs[mt * 16 + q * 4 + r2][(w * 2 + 1) * 16 + m16] = (__bf16)v1;
      }
    __syncthreads();
  }

  // layer 2: K=128
  {
    bf16x8 B0[4], B1[4];
    #pragma unroll
    for (int kc = 0; kc < 4; ++kc) {
      B0[kc] = ld8(W2f + (size_t)(kc * 8 + w * 2 + 0) * 512 + lane * 8);
      B1[kc] = ld8(W2f + (size_t)(kc * 8 + w * 2 + 1) * 512 + lane * 8);
    }
    f32x4 a0[MTILES], a1[MTILES];
    float bv0 = b2[(w * 2) * 16 + m16], bv1 = b2[(w * 2 + 1) * 16 + m16];
    #pragma unroll
    for (int mt = 0; mt < MTILES; ++mt) {
      a0[mt] = (f32x4){bv0, bv0, bv0, bv0};
      a1[mt] = (f32x4){bv1, bv1, bv1, bv1};
      #pragma unroll
      for (int kc = 0; kc < 4; ++kc) {
        bf16x8 av = ld8(&Xs[mt * 16 + m16][kc * 32 + q * 8]);
        a0[mt] = __builtin_amdgcn_mfma_f32_16x16x32_bf16(av, B0[kc], a0[mt], 0, 0, 0);
        a1[mt] = __builtin_amdgcn_mfma_f32_16x16x32_bf16(av, B1[kc], a1[mt], 0, 0, 0);
      }
    }
    __syncthreads();
    #pragma unroll
    for (int mt = 0; mt < MTILES; ++mt)
      #pragma unroll
      for (int r2 = 0; r2 < 4; ++r2) {
        float v0 = a0[mt][r2]; v0 = v0 > 0.f ? v0 : 0.f;
        float v1 = a1[mt][r2]; v1 = v1 > 0.f ? v1 : 0.f;
        Xs[mt * 16 + q * 4 + r2][(w * 2) * 16 + m16]     = (__bf16)v0;
        Xs[mt * 16 + q * 4 + r2][(w * 2 + 1) * 16 + m16] = (__bf16)v1;
      }
    __syncthreads();
  }

  // layer 3: K=128, N=64
  f32x4 a3[MTILES];
  {
    bf16x8 B3[4];
    #pragma unroll
    for (int kc = 0; kc < 4; ++kc)
      B3[kc] = ld8(W3f + (size_t)(kc * 4 + w) * 512 + lane * 8);
    float bv = b3[w * 16 + m16];
    #pragma unroll
    for (int mt = 0; mt < MTILES; ++mt) {
      a3[mt] = (f32x4){bv, bv, bv, bv};
      #pragma unroll
      for (int kc = 0; kc < 4; ++kc) {
        bf16x8 av = ld8(&Xs[mt * 16 + m16][kc * 32 + q * 8]);
        a3[mt] = __builtin_amdgcn_mfma_f32_16x16x32_bf16(av, B3[kc], a3[mt], 0, 0, 0);
      }
    }
  }
  __syncthreads();

  float* Ms = reinterpret_cast<float*>(&Xs[0][0]);
  #pragma unroll
  for (int mt = 0; mt < MTILES; ++mt)
    #pragma unroll
    for (int r2 = 0; r2 < 4; ++r2) {
      int e = mt * 16 + q * 4 + r2;
      Ms[e * 68 + w * 16 + m16] = wexp[e] * a3[mt][r2];
    }
  __syncthreads();

  if (MODE == 0) {
    int node = t >> 4, cg = t & 15;
    int vloc = node >> 3, b = node & 7;
    float4 s4 = make_float4(0.f, 0.f, 0.f, 0.f);
    #pragma unroll
    for (int a1 = 0; a1 < 7; ++a1) {
      int a = a1 + (a1 >= b ? 1 : 0);
      int e = vloc * 56 + a * 7 + b - (b > a ? 1 : 0);
      float4 mv = *reinterpret_cast<const float4*>(Ms + e * 68 + cg * 4);
      s4.x += mv.x; s4.y += mv.y; s4.z += mv.z; s4.w += mv.w;
    }
    *reinterpret_cast<float4*>(xout + (size_t)mloc[node] * 64 + cg * 4) = s4;
  } else {
    constexpr int WIT = (EPB * 16) / 256;
    #pragma unroll
    for (int it = 0; it < WIT; ++it) {
      int idx = t + it * 256;
      int ml = idx >> 4, cg = idx & 15;
      float4 v = *reinterpret_cast<const float4*>(Ms + (ml ^ 1) * 68 + cg * 4);
      *reinterpret_cast<float4*>(xout + (size_t)(e0 + ml) * 64 + cg * 4) = v;
    }
  }
}

// ---------- gru1 + phase-2 attention tail (R14 shape: 256 threads / 64 nodes) ----------
// R15/R16 attribution: the 128-thread/32-node reshape REGRESSED ~45us — the serial
// per-block chain (Z-reduce, staging, gates, attention) amortizes better over 4 waves.
__global__ __launch_bounds__(256) void k_gru_att(
    const float* __restrict__ xt, const float* __restrict__ Zp, int zn,
    float* __restrict__ hbuf, const float* __restrict__ hOther,
    const float* __restrict__ attnW, const float* __restrict__ attnB,
    const __bf16* __restrict__ WiF, const __bf16* __restrict__ WhF,
    const float* __restrict__ bi, const float* __restrict__ bh,
    float* __restrict__ eatt2, float* __restrict__ Zp2)
{
  __shared__ __align__(16) __bf16 xsf[4096];
  __shared__ __align__(16) __bf16 hsf[4096];
  __shared__ float hs32[64][68];
  __shared__ float zred[4];
  __shared__ float zp2s[4];
  const int t = threadIdx.x, lane = t & 63, w = t >> 6;
  const int n0 = blockIdx.x * 64;

  {
    float zs = 0.f;
    for (int i = t; i < zn; i += 256) zs += Zp[i];
    #pragma unroll
    for (int off = 32; off; off >>= 1) zs += __shfl_down(zs, off);
    if (lane == 0) zred[w] = zs;
  }
  __syncthreads();
  const float invZ = 1.0f / (zred[0] + zred[1] + zred[2] + zred[3]);

  {
    const int i = t >> 2, cb = t & 3;
    const float4* xp = (const float4*)(xt + (size_t)(n0 + i) * 64 + cb * 16);
    float4 x4[4] = {xp[0], xp[1], xp[2], xp[3]};
    #pragma unroll
    for (int k = 0; k < 4; ++k) {
      x4[k].x *= invZ; x4[k].y *= invZ; x4[k].z *= invZ; x4[k].w *= invZ;
    }
    const float* xf = (const float*)x4;
    #pragma unroll
    for (int half = 0; half < 2; ++half) {
      __bf16 v8[8];
      #pragma unroll
      for (int j = 0; j < 8; ++j) v8[j] = (__bf16)xf[half * 8 + j];
      int addr = (i >> 4) * 1024 + (cb >> 1) * 512 + ((cb & 1) * 2 + half) * 128 + (i & 15) * 8;
      *(uint4*)(xsf + addr) = *(const uint4*)v8;
    }
    const float4* hp = (const float4*)(hbuf + (size_t)(n0 + i) * 64 + cb * 16);
    float4 h4[4] = {hp[0], hp[1], hp[2], hp[3]};
    *(float4*)(&hs32[i][cb * 16 + 0])  = h4[0];
    *(float4*)(&hs32[i][cb * 16 + 4])  = h4[1];
    *(float4*)(&hs32[i][cb * 16 + 8])  = h4[2];
    *(float4*)(&hs32[i][cb * 16 + 12]) = h4[3];
    const float* hf = (const float*)h4;
    #pragma unroll
    for (int half = 0; half < 2; ++half) {
      __bf16 v8[8];
      #pragma unroll
      for (int j = 0; j < 8; ++j) v8[j] = (__bf16)hf[half * 8 + j];
      int addr = (i >> 4) * 1024 + (cb >> 1) * 512 + ((cb & 1) * 2 + half) * 128 + (i & 15) * 8;
      *(uint4*)(hsf + addr) = *(const uint4*)v8;
    }
  }
  __syncthreads();

  const int m16 = lane & 15, q = lane >> 4;
  f32x4 gi[12], gh[12];
  #pragma unroll
  for (int nt = 0; nt < 12; ++nt) { gi[nt] = (f32x4){0,0,0,0}; gh[nt] = (f32x4){0,0,0,0}; }
  #pragma unroll
  for (int kc = 0; kc < 2; ++kc) {
    bf16x8 ax = ld8(xsf + w * 1024 + kc * 512 + lane * 8);
    bf16x8 ah = ld8(hsf + w * 1024 + kc * 512 + lane * 8);
    #pragma unroll
    for (int nt = 0; nt < 12; ++nt) {
      bf16x8 bx = ld8(WiF + (size_t)(kc * 12 + nt) * 512 + lane * 8);
      gi[nt] = __builtin_amdgcn_mfma_f32_16x16x32_bf16(ax, bx, gi[nt], 0, 0, 0);
      bf16x8 bh8 = ld8(WhF + (size_t)(kc * 12 + nt) * 512 + lane * 8);
      gh[nt] = __builtin_amdgcn_mfma_f32_16x16x32_bf16(ah, bh8, gh[nt], 0, 0, 0);
    }
  }

  #pragma unroll
  for (int nt = 0; nt < 4; ++nt) {
    int o = nt * 16 + m16;
    float bir = bi[o]       + bh[o];
    float biz = bi[64 + o]  + bh[64 + o];
    float bin = bi[128 + o], bhn = bh[128 + o];
    #pragma unroll
    for (int r = 0; r < 4; ++r) {
      int nl = w * 16 + q * 4 + r;
      float rg = sigm(gi[nt][r]     + gh[nt][r]     + bir);
      float zg = sigm(gi[nt + 4][r] + gh[nt + 4][r] + biz);
      float ng = tanhf(gi[nt + 8][r] + bin + rg * (gh[nt + 8][r] + bhn));
      float ho = hs32[nl][o];
      float res = (1.f - zg) * ng + zg * ho;
      hbuf[(size_t)(n0 + nl) * 64 + o] = res;
      hs32[nl][o] = res;                       // keep fp32 h_new for the attention tail
    }
  }
  __syncthreads();

  // ---- phase-2 attention: le = attnW[0:64].h_new[e] + attnW[64:128].h_f2v[e^1] + b ----
  {
    int e = w * 16 + (lane >> 2), part = lane & 3;
    float s = 0.f;
    if (part < 2) {
      #pragma unroll
      for (int j = 0; j < 32; ++j) s += attnW[part * 32 + j] * hs32[e][part * 32 + j];
    } else {
      const float* hj = hOther + (size_t)((n0 + e) ^ 1) * 64 + (part - 2) * 32;
      #pragma unroll
      for (int j = 0; j < 32; ++j) s += attnW[64 + (part - 2) * 32 + j] * hj[j];
    }
    s += __shfl_xor(s, 1); s += __shfl_xor(s, 2);
    float ex = 0.f;
    if (part == 0) {
      float le = s + attnB[0];
      le = le > 0.f ? le : 0.01f * le;
      ex = expf(le);
      eatt2[n0 + e] = ex;
    }
    #pragma unroll
    for (int off = 4; off < 64; off <<= 1) ex += __shfl_xor(ex, off);
    if (lane == 0) zp2s[w] = ex;
  }
  __syncthreads();
  if (t == 0) Zp2[blockIdx.x] = zp2s[0] + zp2s[1] + zp2s[2] + zp2s[3];
}

// ---------- FUSED mlp2 + gru2: weighted messages never leave LDS ----------
__global__ __launch_bounds__(256) void k_fuse(
    const float* __restrict__ hV, float* __restrict__ hF,
    const float* __restrict__ feat,
    const float* __restrict__ eatt2, const float* __restrict__ Zp2,
    const __bf16* __restrict__ W1f, const float* __restrict__ b1,
    const __bf16* __restrict__ W2f, const float* __restrict__ b2,
    const __bf16* __restrict__ W3f, const float* __restrict__ b3,
    const __bf16* __restrict__ WiF, const __bf16* __restrict__ WhF,
    const float* __restrict__ bi, const float* __restrict__ bh)
{
  __shared__ __align__(16) __bf16 Xs[64][168];   // 21504 B; aliased as fp32 Ms later
  __shared__ __align__(16) float hs32[64][68];   // 17408 B (old h_f2v, fp32)
  __shared__ __align__(16) __bf16 xsf[4096];     // 8192 B (GRU x frags)
  __shared__ __align__(16) __bf16 hsf[4096];     // 8192 B (GRU h frags)
  __shared__ float wexp[64];
  __shared__ float zred[4];
  const int t = threadIdx.x, lane = t & 63, w = t >> 6;
  const int n0 = blockIdx.x * 64;
  const int m16 = lane & 15, q = lane >> 4;

  // Z2 reduce (256 slots, 1 per thread)
  {
    float zs = Zp2[t];
    #pragma unroll
    for (int off = 32; off; off >>= 1) zs += __shfl_down(zs, off);
    if (lane == 0) zred[w] = zs;
  }
  if (t < 64) wexp[t] = eatt2[n0 + t];

  // stage Xs (hi = h_v2f[m], hj = h_f2v[m^1], feat) + hs32 (old h_f2v[m], fp32)
  {
    const int half = lane >> 5, l2 = lane & 31;
    const int r0 = w * 16;
    #pragma unroll
    for (int i = 0; i < 16; ++i) {
      int e = r0 + i;
      const float* src = half ? (hF + (size_t)((n0 + e) ^ 1) * 64)
                              : (hV + (size_t)(n0 + e) * 64);
      float2 v = *reinterpret_cast<const float2*>(src + l2 * 2);
      union { __bf16 b[2]; unsigned u; } cv;
      cv.b[0] = (__bf16)v.x; cv.b[1] = (__bf16)v.y;
      *reinterpret_cast<unsigned*>(&Xs[e][half * 64 + l2 * 2]) = cv.u;
    }
    #pragma unroll
    for (int it = 0; it < 8; ++it) {
      int e = r0 + it * 2 + (lane >> 5);
      int f = lane & 31;
      float fv = (f < 4) ? feat[(size_t)(n0 + e) * 4 + f] : 0.f;
      Xs[e][128 + f] = (__bf16)fv;
    }
  }
  {
    const int i = t >> 2, cb = t & 3;
    const float4* hp = (const float4*)(hF + (size_t)(n0 + i) * 64 + cb * 16);
    *(float4*)(&hs32[i][cb * 16 + 0])  = hp[0];
    *(float4*)(&hs32[i][cb * 16 + 4])  = hp[1];
    *(float4*)(&hs32[i][cb * 16 + 8])  = hp[2];
    *(float4*)(&hs32[i][cb * 16 + 12]) = hp[3];
  }
  __syncthreads();
  const float invZ = 1.0f / (zred[0] + zred[1] + zred[2] + zred[3]);

  // ---- mlp2 layer 1: K=160 ----
  {
    bf16x8 B0[5], B1[5];
    #pragma unroll
    for (int kc = 0; kc < 5; ++kc) {
      B0[kc] = ld8(W1f + (size_t)(kc * 8 + w * 2 + 0) * 512 + lane * 8);
      B1[kc] = ld8(W1f + (size_t)(kc * 8 + w * 2 + 1) * 512 + lane * 8);
    }
    f32x4 a0[4], a1[4];
    float bv0 = b1[(w * 2) * 16 + m16], bv1 = b1[(w * 2 + 1) * 16 + m16];
    #pragma unroll
    for (int mt = 0; mt < 4; ++mt) {
      a0[mt] = (f32x4){bv0, bv0, bv0, bv0};
      a1[mt] = (f32x4){bv1, bv1, bv1, bv1};
      #pragma unroll
      for (int kc = 0; kc < 5; ++kc) {
        bf16x8 av = ld8(&Xs[mt * 16 + m16][kc * 32 + q * 8]);
        a0[mt] = __builtin_amdgcn_mfma_f32_16x16x32_bf16(av, B0[kc], a0[mt], 0, 0, 0);
        a1[mt] = __builtin_amdgcn_mfma_f32_16x16x32_bf16(av, B1[kc], a1[mt], 0, 0, 0);
      }
    }
    __syncthreads();
    #pragma unroll
    for (int mt = 0; mt < 4; ++mt)
      #pragma unroll
      for (int r2 = 0; r2 < 4; ++r2) {
        float v0 = a0[mt][r2]; v0 = v0 > 0.f ? v0 : 0.f;
        float v1 = a1[mt][r2]; v1 = v1 > 0.f ? v1 : 0.f;
        Xs[mt * 16 + q * 4 + r2][(w * 2) * 16 + m16]     = (__bf16)v0;
        Xs[mt * 16 + q * 4 + r2][(w * 2 + 1) * 16 + m16] = (__bf16)v1;
      }
    __syncthreads();
  }

  // ---- mlp2 layer 2: K=128 ----
  {
    bf16x8 B0[4], B1[4];
    #pragma unroll
    for (int kc = 0; kc < 4; ++kc) {
      B0[kc] = ld8(W2f + (size_t)(kc * 8 + w * 2 + 0) * 512 + lane * 8);
      B1[kc] = ld8(W2f + (size_t)(kc * 8 + w * 2 + 1) * 512 + lane * 8);
    }
    f32x4 a0[4], a1[4];
    float bv0 = b2[(w * 2) * 16 + m16], bv1 = b2[(w * 2 + 1) * 16 + m16];
    #pragma unroll
    for (int mt = 0; mt < 4; ++mt) {
      a0[mt] = (f32x4){bv0, bv0, bv0, bv0};
      a1[mt] = (f32x4){bv1, bv1, bv1, bv1};
      #pragma unroll
      for (int kc = 0; kc < 4; ++kc) {
        bf16x8 av = ld8(&Xs[mt * 16 + m16][kc * 32 + q * 8]);
        a0[mt] = __builtin_amdgcn_mfma_f32_16x16x32_bf16(av, B0[kc], a0[mt], 0, 0, 0);
        a1[mt] = __builtin_amdgcn_mfma_f32_16x16x32_bf16(av, B1[kc], a1[mt], 0, 0, 0);
      }
    }
    __syncthreads();
    #pragma unroll
    for (int mt = 0; mt < 4; ++mt)
      #pragma unroll
      for (int r2 = 0; r2 < 4; ++r2) {
        float v0 = a0[mt][r2]; v0 = v0 > 0.f ? v0 : 0.f;
        float v1 = a1[mt][r2]; v1 = v1 > 0.f ? v1 : 0.f;
        Xs[mt * 16 + q * 4 + r2][(w * 2) * 16 + m16]     = (__bf16)v0;
        Xs[mt * 16 + q * 4 + r2][(w * 2 + 1) * 16 + m16] = (__bf16)v1;
      }
    __syncthreads();
  }

  // ---- mlp2 layer 3: K=128, N=64 -> weighted msg into LDS Ms ----
  f32x4 a3[4];
  {
    bf16x8 B3[4];
    #pragma unroll
    for (int kc = 0; kc < 4; ++kc)
      B3[kc] = ld8(W3f + (size_t)(kc * 4 + w) * 512 + lane * 8);
    float bv = b3[w * 16 + m16];
    #pragma unroll
    for (int mt = 0; mt < 4; ++mt) {
      a3[mt] = (f32x4){bv, bv, bv, bv};
      #pragma unroll
      for (int kc = 0; kc < 4; ++kc) {
        bf16x8 av = ld8(&Xs[mt * 16 + m16][kc * 32 + q * 8]);
        a3[mt] = __builtin_amdgcn_mfma_f32_16x16x32_bf16(av, B3[kc], a3[mt], 0, 0, 0);
      }
    }
  }
  __syncthreads();
  float* Ms = reinterpret_cast<float*>(&Xs[0][0]);
  #pragma unroll
  for (int mt = 0; mt < 4; ++mt)
    #pragma unroll
    for (int r2 = 0; r2 < 4; ++r2) {
      int e = mt * 16 + q * 4 + r2;
      Ms[e * 68 + w * 16 + m16] = wexp[e] * a3[mt][r2];
    }
  __syncthreads();

  // ---- gru2: x[m] = Ms[m^1] * invZ; h from hs32 ----
  {
    const int i = t >> 2, cb = t & 3;
    float x16[16];
    #pragma unroll
    for (int k4 = 0; k4 < 4; ++k4) {
      float4 v = *reinterpret_cast<const float4*>(Ms + (i ^ 1) * 68 + cb * 16 + k4 * 4);
      x16[k4 * 4 + 0] = v.x * invZ; x16[k4 * 4 + 1] = v.y * invZ;
      x16[k4 * 4 + 2] = v.z * invZ; x16[k4 * 4 + 3] = v.w * invZ;
    }
    #pragma unroll
    for (int half = 0; half < 2; ++half) {
      __bf16 v8[8];
      #pragma unroll
      for (int j = 0; j < 8; ++j) v8[j] = (__bf16)x16[half * 8 + j];
      int addr = (i >> 4) * 1024 + (cb >> 1) * 512 + ((cb & 1) * 2 + half) * 128 + (i & 15) * 8;
      *(uint4*)(xsf + addr) = *(const uint4*)v8;
    }
    #pragma unroll
    for (int half = 0; half < 2; ++half) {
      __bf16 v8[8];
      #pragma unroll
      for (int j = 0; j < 8; ++j) v8[j] = (__bf16)hs32[i][cb * 16 + half * 8 + j];
      int addr = (i >> 4) * 1024 + (cb >> 1) * 512 + ((cb & 1) * 2 + half) * 128 + (i & 15) * 8;
      *(uint4*)(hsf + addr) = *(const uint4*)v8;
    }
  }
  __syncthreads();

  f32x4 gi[12], gh[12];
  #pragma unroll
  for (int nt = 0; nt < 12; ++nt) { gi[nt] = (f32x4){0,0,0,0}; gh[nt] = (f32x4){0,0,0,0}; }
  #pragma unroll
  for (int kc = 0; kc < 2; ++kc) {
    bf16x8 ax = ld8(xsf + w * 1024 + kc * 512 + lane * 8);
    bf16x8 ah = ld8(hsf + w * 1024 + kc * 512 + lane * 8);
    #pragma unroll
    for (int nt = 0; nt < 12; ++nt) {
      bf16x8 bx = ld8(WiF + (size_t)(kc * 12 + nt) * 512 + lane * 8);
      gi[nt] = __builtin_amdgcn_mfma_f32_16x16x32_bf16(ax, bx, gi[nt], 0, 0, 0);
      bf16x8 bh8 = ld8(WhF + (size_t)(kc * 12 + nt) * 512 + lane * 8);
      gh[nt] = __builtin_amdgcn_mfma_f32_16x16x32_bf16(ah, bh8, gh[nt], 0, 0, 0);
    }
  }

  #pragma unroll
  for (int nt = 0; nt < 4; ++nt) {
    int o = nt * 16 + m16;
    float bir = bi[o]       + bh[o];
    float biz = bi[64 + o]  + bh[64 + o];
    float bin = bi[128 + o], bhn = bh[128 + o];
    #pragma unroll
    for (int r = 0; r < 4; ++r) {
      int nl = w * 16 + q * 4 + r;
      float rg = sigm(gi[nt][r]     + gh[nt][r]     + bir);
      float zg = sigm(gi[nt + 4][r] + gh[nt + 4][r] + biz);
      float ng = tanhf(gi[nt + 8][r] + bin + rg * (gh[nt + 8][r] + bhn));
      float ho = hs32[nl][o];
      hF[(size_t)(n0 + nl) * 64 + o] = (1.f - zg) * ng + zg * ho;
    }
  }
}

// ---------- fused node-sum + readout MLP ----------
__global__ __launch_bounds__(256) void k_readout(
    const float* __restrict__ f2v_h, const int* __restrict__ f2v_col,
    const __bf16* __restrict__ W1f, const float* __restrict__ b1,
    const __bf16* __restrict__ W2f, const float* __restrict__ b2,
    const __bf16* __restrict__ W3f, const float* __restrict__ b3,
    float* __restrict__ out)
{
  __shared__ __align__(16) __bf16 Xs[64][136];
  const int t = threadIdx.x, lane = t & 63, w = t >> 6;
  const int r0 = w * 16;
  const int v0 = blockIdx.x * 64;

  #pragma unroll
  for (int i = 0; i < 16; ++i) {
    int v = v0 + r0 + i;
    float s = 0.f;
    #pragma unroll
    for (int b = 0; b < 8; ++b) {
      int m = f2v_col[v * 56 + (b == 0 ? 7 : (b - 1))];
      s += f2v_h[(size_t)m * 64 + lane];
    }
    Xs[r0 + i][lane] = (__bf16)s;
  }

  const int m16 = lane & 15, q = lane >> 4;

  {
    f32x4 acc[8];
    #pragma unroll
    for (int nt = 0; nt < 8; ++nt) {
      float bv = b1[nt * 16 + m16];
      acc[nt] = (f32x4){bv, bv, bv, bv};
    }
    #pragma unroll
    for (int kc = 0; kc < 2; ++kc) {
      bf16x8 av = ld8(&Xs[r0 + m16][kc * 32 + q * 8]);
      #pragma unroll
      for (int nt = 0; nt < 8; ++nt) {
        bf16x8 bv = ld8(W1f + (size_t)(kc * 8 + nt) * 512 + lane * 8);
        acc[nt] = __builtin_amdgcn_mfma_f32_16x16x32_bf16(av, bv, acc[nt], 0, 0, 0);
      }
    }
    #pragma unroll
    for (int nt = 0; nt < 8; ++nt)
      #pragma unroll
      for (int r2 = 0; r2 < 4; ++r2) {
        float v = acc[nt][r2]; v = v > 0.f ? v : 0.f;
        Xs[r0 + q * 4 + r2][nt * 16 + m16] = (__bf16)v;
      }
  }

  {
    f32x4 acc[8];
    #pragma unroll
    for (int nt = 0; nt < 8; ++nt) {
      float bv = b2[nt * 16 + m16];
      acc[nt] = (f32x4){bv, bv, bv, bv};
    }
    #pragma unroll
    for (int kc = 0; kc < 4; ++kc) {
      bf16x8 av = ld8(&Xs[r0 + m16][kc * 32 + q * 8]);
      #pragma unroll
      for (int nt = 0; nt < 8; ++nt) {
        bf16x8 bv = ld8(W2f + (size_t)(kc * 8 + nt) * 512 + lane * 8);
        acc[nt] = __builtin_amdgcn_mfma_f32_16x16x32_bf16(av, bv, acc[nt], 0, 0, 0);
      }
    }
    #pragma unroll
    for (int nt = 0; nt < 8; ++nt)
      #pragma unroll
      for (int r2 = 0; r2 < 4; ++r2) {
        float v = acc[nt][r2]; v = v > 0.f ? v : 0.f;
        Xs[r0 + q * 4 + r2][nt * 16 + m16] = (__bf16)v;
      }
  }

  {
    f32x4 acc = (f32x4){0, 0, 0, 0};
    if (m16 < 2) { float bv = b3[m16]; acc = (f32x4){bv, bv, bv, bv}; }
    #pragma unroll
    for (int kc = 0; kc < 4; ++kc) {
      bf16x8 av = ld8(&Xs[r0 + m16][kc * 32 + q * 8]);
      bf16x8 bv = ld8(W3f + (size_t)kc * 512 + lane * 8);
      acc = __builtin_amdgcn_mfma_f32_16x16x32_bf16(av, bv, acc, 0, 0, 0);
    }
    #pragma unroll
    for (int r = 0; r < 4; ++r) {
      float other = __shfl_xor(acc[r], 1);
      if (m16 == 0) {
        float l0 = acc[r], l1 = other;
        float mx = fmaxf(l0, l1);
        float p0 = expf(l0 - mx), p1 = expf(l1 - mx);
        float inv = 1.0f / (p0 + p1);
        int v = v0 + r0 + q * 4 + r;
        *reinterpret_cast<float2*>(out + (size_t)v * 2) = make_float2(p0 * inv, p1 * inv);
      }
    }
  }
}

extern "C" void kernel_launch(void* const* d_in, const int* in_sizes, int n_in,
                              void* d_out, int out_size, void* d_ws, size_t ws_size,
                              hipStream_t stream) {
  const float* attn_W = (const float*)d_in[0];
  const float* attn_b = (const float*)d_in[1];
  const float* v2f_W1 = (const float*)d_in[2];
  const float* v2f_b1 = (const float*)d_in[3];
  const float* v2f_W2 = (const float*)d_in[4];
  const float* v2f_b2 = (const float*)d_in[5];
  const float* v2f_W3 = (const float*)d_in[6];
  const float* v2f_b3 = (const float*)d_in[7];
  const float* f2v_W1 = (const float*)d_in[8];
  const float* f2v_b1 = (const float*)d_in[9];
  const float* f2v_W2 = (const float*)d_in[10];
  const float* f2v_b2 = (const float*)d_in[11];
  const float* f2v_W3 = (const float*)d_in[12];
  const float* f2v_b3 = (const float*)d_in[13];
  const float* ro_W1  = (const float*)d_in[14];
  const float* ro_b1  = (const float*)d_in[15];
  const float* ro_W2  = (const float*)d_in[16];
  const float* ro_b2  = (const float*)d_in[17];
  const float* ro_W3  = (const float*)d_in[18];
  const float* ro_b3  = (const float*)d_in[19];
  const float* gv_Wi  = (const float*)d_in[20];
  const float* gv_Wh  = (const float*)d_in[21];
  const float* gv_bi  = (const float*)d_in[22];
  const float* gv_bh  = (const float*)d_in[23];
  const float* gf_Wi  = (const float*)d_in[24];
  const float* gf_Wh  = (const float*)d_in[25];
  const float* gf_bi  = (const float*)d_in[26];
  const float* gf_bh  = (const float*)d_in[27];
  const float* feat5  = (const float*)d_in[28];
  const float* feat4  = (const float*)d_in[29];
  const int* f2v_row  = (const int*)d_in[30];
  const int* f2v_col  = (const int*)d_in[31];

  float* ws = (float*)d_ws;
  float* xt1    = ws;                                    // M*64
  float* h_v2f  = xt1 + (size_t)MMC * 64;                // M*64
  float* h_f2v  = h_v2f + (size_t)MMC * 64;              // M*64
  float* Zp1    = h_f2v + (size_t)MMC * 64;              // 1024
  float* Zp2    = Zp1 + 1024;                            // 256
  float* eatt2  = Zp2 + 256;                             // MMC
  __bf16* wbuf  = (__bf16*)(((uintptr_t)(eatt2 + MMC) + 15) & ~(uintptr_t)15);
  __bf16* w1v = wbuf;            // 20480
  __bf16* w2v = w1v + 20480;     // 16384
  __bf16* w3v = w2v + 16384;     //  8192
  __bf16* w1f = w3v + 8192;      // 20480
  __bf16* w2f = w1f + 20480;     // 16384
  __bf16* w3f = w2f + 16384;     //  8192
  __bf16* wiv = w3f + 8192;      // 12288
  __bf16* whv = wiv + 12288;     // 12288
  __bf16* wif = whv + 12288;     // 12288
  __bf16* whf = wif + 12288;     // 12288
  __bf16* wr1 = whf + 12288;     //  8192
  __bf16* wr2 = wr1 + 8192;      // 16384
  __bf16* wr3 = wr2 + 16384;     //  2048

  hipMemsetAsync(h_v2f, 0, (size_t)2 * MMC * 64 * sizeof(float), stream);

  {
    PrepJobs J;
    const float* srcs[NJOBS] = {v2f_W1, v2f_W2, v2f_W3, f2v_W1, f2v_W2, f2v_W3,
                                gv_Wi, gv_Wh, gf_Wi, gf_Wh, ro_W1, ro_W2, ro_W3};
    int kin[NJOBS]  = {133, 128, 128, 132, 128, 128, 64, 64, 64, 64, 64, 128, 128};
    int nin[NJOBS]  = {128, 128, 64, 128, 128, 64, 192, 192, 192, 192, 128, 128, 2};
    int nt[NJOBS]   = {8, 8, 4, 8, 8, 4, 12, 12, 12, 12, 8, 8, 1};
    int size[NJOBS] = {20480, 16384, 8192, 20480, 16384, 8192,
                       12288, 12288, 12288, 12288, 8192, 16384, 2048};
    int cum = 0;
    for (int i = 0; i < NJOBS; ++i) {
      J.src[i] = srcs[i]; J.kin[i] = kin[i]; J.nin[i] = nin[i]; J.ntile[i] = nt[i];
      J.base[i] = cum; cum += size[i];
    }
    J.dst0 = wbuf; J.total = cum;   // 165888
    k_prep_all<<<(cum + 255) / 256, 256, 0, stream>>>(J);
  }

  const int ZN1 = E1C / 112;        // 1024 block slots, phase 1

  for (int s = 0; s < NSTEPS; ++s) {
    // phase 1: edge MLP + in-block aggregation (112-edge = 2-variable tiles)
    k_mlp<5, 112, 0><<<E1C / 112, 256, 0, stream>>>(
        h_f2v, h_v2f, f2v_row, f2v_col, feat5,
        w1v, v2f_b1, w2v, v2f_b2, w3v, v2f_b3,
        attn_W, attn_b, xt1, Zp1);
    // gru1 (h_v2f update) + phase-2 attention (fp32 h) -> eatt2, Zp2 (256 blocks)
    k_gru_att<<<MMC / 64, 256, 0, stream>>>(
        xt1, Zp1, ZN1, h_v2f, h_f2v, attn_W, attn_b,
        wiv, whv, gv_bi, gv_bh, eatt2, Zp2);
    // fused mlp2 + gru2 (weighted msgs stay in LDS; h_f2v update)
    k_fuse<<<MMC / 64, 256, 0, stream>>>(
        h_v2f, h_f2v, feat4, eatt2, Zp2,
        w1f, f2v_b1, w2f, f2v_b2, w3f, f2v_b3,
        wif, whf, gf_bi, gf_bh);
  }
  k_readout<<<NVC / 64, 256, 0, stream>>>(h_f2v, f2v_col,
                                          wr1, ro_b1, wr2, ro_b2, wr3, ro_b3,
                                          (float*)d_out);
}